// Round 1
// baseline (252.771 us; speedup 1.0000x reference)
//
#include <hip/hip_runtime.h>
#include <math.h>

// Problem constants (from reference setup_inputs)
#define BATCH 32
#define NPTS  4096
#define DCH   254            // input channels; output row = DCH + 2 = 256
#define OUTC  256
#define PB    32             // partial-reduce blocks per batch
#define EPSV  1e-5f

// ---------------------------------------------------------------------------
// Kernel 1: per-batch partial reduction of sum / sumsq.
// Grid = BATCH*PB blocks x 256 threads. Block (b, j) strides over batch b's
// 260,096 float4s. Each slot of `partials` is written unconditionally, so the
// 0xAA-poisoned workspace needs no zero-init.
// ---------------------------------------------------------------------------
__global__ __launch_bounds__(256) void ipn_reduce(const float* __restrict__ x,
                                                  float2* __restrict__ partials) {
    const int b = blockIdx.x / PB;
    const int j = blockIdx.x % PB;
    const float4* xb = (const float4*)(x + (size_t)b * (NPTS * DCH));
    const int n4 = (NPTS * DCH) / 4;   // 260096, and the batch base is 16B-aligned

    float s = 0.f, ss = 0.f;
    for (int i = j * 256 + threadIdx.x; i < n4; i += PB * 256) {
        float4 v = xb[i];
        s  += (v.x + v.y) + (v.z + v.w);
        ss += (v.x * v.x + v.y * v.y) + (v.z * v.z + v.w * v.w);
    }
    // wave64 shuffle reduce
    #pragma unroll
    for (int off = 32; off > 0; off >>= 1) {
        s  += __shfl_down(s, off);
        ss += __shfl_down(ss, off);
    }
    __shared__ float ls[4], lss[4];
    const int wave = threadIdx.x >> 6;
    if ((threadIdx.x & 63) == 0) { ls[wave] = s; lss[wave] = ss; }
    __syncthreads();
    if (threadIdx.x == 0) {
        float S  = (ls[0]  + ls[1])  + (ls[2]  + ls[3]);
        float SS = (lss[0] + lss[1]) + (lss[2] + lss[3]);
        partials[blockIdx.x] = make_float2(S, SS);
    }
}

// ---------------------------------------------------------------------------
// Kernel 2: combine PB partials per batch -> stats[b] = {mean, std, 1/(std+eps)}
// Grid = BATCH blocks x 64 threads (one wave).
// ---------------------------------------------------------------------------
__global__ __launch_bounds__(64) void ipn_finalize(const float2* __restrict__ partials,
                                                   float* __restrict__ stats) {
    const int b = blockIdx.x;
    const int l = threadIdx.x;
    float s = 0.f, ss = 0.f;
    if (l < PB) {
        float2 p = partials[b * PB + l];
        s = p.x; ss = p.y;
    }
    #pragma unroll
    for (int off = 32; off > 0; off >>= 1) {
        s  += __shfl_down(s, off);
        ss += __shfl_down(ss, off);
    }
    if (l == 0) {
        const float invM = 1.0f / (float)(NPTS * DCH);
        float mean = s * invM;
        float var  = fmaxf(ss * invM - mean * mean, 0.f);   // biased variance
        float stdv = sqrtf(var);
        stats[b * 4 + 0] = mean;
        stats[b * 4 + 1] = stdv;
        stats[b * 4 + 2] = 1.0f / (stdv + EPSV);
    }
}

// ---------------------------------------------------------------------------
// Kernel 3: normalize + concat(mean,std) + scale/bias.
// One wave per output row of 256 floats: lane l owns cols 4l..4l+3.
// Output stores are float4-aligned (row stride 1024 B). Input row stride is
// 1016 B (not 16B-aligned) -> 4 coalesced dword loads per lane instead.
// Lane 63 splices mean (col 254) and std (col 255).
// weights/biases are loaded once per thread (lane->col mapping is loop-invariant).
// ---------------------------------------------------------------------------
__global__ __launch_bounds__(256) void ipn_norm(const float* __restrict__ x,
                                                const float* __restrict__ w,
                                                const float* __restrict__ bias,
                                                const float* __restrict__ stats,
                                                float* __restrict__ out) {
    const int lane = threadIdx.x & 63;
    const int c0   = lane * 4;
    const float4 w4 = ((const float4*)w)[lane];
    const float4 b4 = ((const float4*)bias)[lane];

    const int wave       = threadIdx.x >> 6;
    const int waves_blk  = blockDim.x >> 6;                 // 4
    const int row_stride = gridDim.x * waves_blk;
    const int total_rows = BATCH * NPTS;

    for (int row = blockIdx.x * waves_blk + wave; row < total_rows; row += row_stride) {
        const int b = row >> 12;                            // NPTS = 4096
        const float mean = stats[b * 4 + 0];
        const float stdv = stats[b * 4 + 1];
        const float inv  = stats[b * 4 + 2];

        const float* xr = x + (size_t)row * DCH + c0;
        float4 v;
        if (c0 < 252) {
            v.x = (xr[0] - mean) * inv;
            v.y = (xr[1] - mean) * inv;
            v.z = (xr[2] - mean) * inv;
            v.w = (xr[3] - mean) * inv;
        } else {                                            // lane 63: cols 252,253,254,255
            v.x = (xr[0] - mean) * inv;
            v.y = (xr[1] - mean) * inv;
            v.z = mean;
            v.w = stdv;
        }
        float4 o;
        o.x = v.x * w4.x + b4.x;
        o.y = v.y * w4.y + b4.y;
        o.z = v.z * w4.z + b4.z;
        o.w = v.w * w4.w + b4.w;
        ((float4*)(out + (size_t)row * OUTC))[lane] = o;
    }
}

// ---------------------------------------------------------------------------
extern "C" void kernel_launch(void* const* d_in, const int* in_sizes, int n_in,
                              void* d_out, int out_size, void* d_ws, size_t ws_size,
                              hipStream_t stream) {
    const float* x    = (const float*)d_in[0];   // [32, 4096, 254] fp32
    const float* wgt  = (const float*)d_in[1];   // [256] fp32
    const float* bia  = (const float*)d_in[2];   // [256] fp32
    float* out        = (float*)d_out;           // [32, 4096, 256] fp32

    float2* partials = (float2*)d_ws;                        // 1024 * 8 B = 8 KB
    float*  stats    = (float*)((char*)d_ws + BATCH * PB * sizeof(float2)); // 32*4 floats

    ipn_reduce<<<BATCH * PB, 256, 0, stream>>>(x, partials);
    ipn_finalize<<<BATCH, 64, 0, stream>>>(partials, stats);
    ipn_norm<<<4096, 256, 0, stream>>>(x, wgt, bia, stats, out);
}